// Round 1
// baseline (1339.618 us; speedup 1.0000x reference)
//
#include <hip/hip_runtime.h>
#include <hip/hip_bf16.h>
#include <math.h>

// Problem: B=2,H=12 -> 24 heads, S=2048, D=64, fp32.
// out = concat(context[24,2048,64], attn[24,2048,2048]) fp32.
//
// Round 1: correct fp32-VALU baseline, two-pass (Z then attn+PV), reg-blocked.
// Deliberately plain fp32 scores: the absmax result calibrates the mask-flip
// (scores>=0 sign test) precision budget for later MFMA split-bf16 rounds.

#define S_LEN 2048
#define DK    64
#define MT    32          // q-rows per workgroup
#define KT    128         // k-cols per tile
#define NKT   (S_LEN / KT)
#define QPAD  68          // 64 + 4 floats: keeps 16B alignment, breaks pow2 stride
#define KPAD  68
#define EPAD  132         // 128 + 4

__global__ __launch_bounds__(256, 2)
void sdpa_kernel(const float* __restrict__ Q, const float* __restrict__ K,
                 const float* __restrict__ V, float* __restrict__ ctx_out,
                 float* __restrict__ attn_out) {
  __shared__ float Qs[MT][QPAD];
  __shared__ float Ks[KT][KPAD];
  __shared__ float es[MT][EPAD];     // pass A: overlaid as z-partials; pass B: e-tile
  __shared__ float zinv_s[MT];

  const int head = blockIdx.y;                 // 0..23
  const int q0   = blockIdx.x * MT;
  const int tid  = threadIdx.x;
  const int tq   = tid >> 5;                   // 0..7  -> q-rows 4*tq..4*tq+3
  const int tk   = tid & 31;                   // 0..31 -> k-cols tk+32*j, j=0..3

  const float* Qh = Q + (size_t)head * S_LEN * DK;
  const float* Kh = K + (size_t)head * S_LEN * DK;
  const float* Vh = V + (size_t)head * S_LEN * DK;

  // ---- load Q tile (32x64 = 512 float4, 2 per thread), coalesced ----
  #pragma unroll
  for (int r = 0; r < 2; ++r) {
    int f   = tid + 256 * r;                   // 0..511
    int row = f >> 4;                          // 16 float4 per row
    int c4  = (f & 15) << 2;
    float4 v = *(const float4*)(Qh + (size_t)(q0 + row) * DK + c4);
    *(float4*)&Qs[row][c4] = v;
  }

  float zpart[4] = {0.f, 0.f, 0.f, 0.f};

  // ================= pass A: row sums Z =================
  for (int kt = 0; kt < NKT; ++kt) {
    __syncthreads();                           // Ks reuse guard
    #pragma unroll
    for (int r = 0; r < 8; ++r) {              // stage K tile: 2048 float4
      int f   = tid + 256 * r;
      int row = f >> 4;
      int c4  = (f & 15) << 2;
      float4 v = *(const float4*)(Kh + (size_t)(kt * KT + row) * DK + c4);
      *(float4*)&Ks[row][c4] = v;
    }
    __syncthreads();

    float acc[4][4] = {};
    #pragma unroll
    for (int dc = 0; dc < 16; ++dc) {
      float4 qv[4], kv[4];
      #pragma unroll
      for (int i = 0; i < 4; ++i) qv[i] = *(const float4*)&Qs[4 * tq + i][4 * dc];
      #pragma unroll
      for (int j = 0; j < 4; ++j) kv[j] = *(const float4*)&Ks[tk + 32 * j][4 * dc];
      #pragma unroll
      for (int i = 0; i < 4; ++i)
        #pragma unroll
        for (int j = 0; j < 4; ++j) {
          acc[i][j] = fmaf(qv[i].x, kv[j].x, acc[i][j]);
          acc[i][j] = fmaf(qv[i].y, kv[j].y, acc[i][j]);
          acc[i][j] = fmaf(qv[i].z, kv[j].z, acc[i][j]);
          acc[i][j] = fmaf(qv[i].w, kv[j].w, acc[i][j]);
        }
    }
    #pragma unroll
    for (int i = 0; i < 4; ++i)
      #pragma unroll
      for (int j = 0; j < 4; ++j) {
        // mask: score>=0 (<=> dot>=0, scale is +pow2) -> e=0; else exp(dot/8)
        float e = (acc[i][j] < 0.0f) ? __expf(acc[i][j] * 0.125f) : 0.0f;
        zpart[i] += e;
      }
  }

  // ---- Z reduction (z-partials overlaid on es, unused in pass A) ----
  float* zs = &es[0][0];                       // [32 rows][32 tk]
  __syncthreads();
  #pragma unroll
  for (int i = 0; i < 4; ++i) zs[(4 * tq + i) * 32 + tk] = zpart[i];
  __syncthreads();
  if (tid < 32) {
    float z = 0.f;
    #pragma unroll 8
    for (int t = 0; t < 32; ++t) z += zs[tid * 32 + t];
    zinv_s[tid] = 1.0f / (z + 1e-8f);
  }
  __syncthreads();
  float zi[4];
  #pragma unroll
  for (int i = 0; i < 4; ++i) zi[i] = zinv_s[4 * tq + i];

  // ================= pass B: attn write + PV =================
  float Cacc[4][2] = {};
  for (int kt = 0; kt < NKT; ++kt) {
    __syncthreads();                           // es/Ks reuse guard (PV readers done)
    #pragma unroll
    for (int r = 0; r < 8; ++r) {
      int f   = tid + 256 * r;
      int row = f >> 4;
      int c4  = (f & 15) << 2;
      float4 v = *(const float4*)(Kh + (size_t)(kt * KT + row) * DK + c4);
      *(float4*)&Ks[row][c4] = v;
    }
    __syncthreads();

    float acc[4][4] = {};
    #pragma unroll
    for (int dc = 0; dc < 16; ++dc) {
      float4 qv[4], kv[4];
      #pragma unroll
      for (int i = 0; i < 4; ++i) qv[i] = *(const float4*)&Qs[4 * tq + i][4 * dc];
      #pragma unroll
      for (int j = 0; j < 4; ++j) kv[j] = *(const float4*)&Ks[tk + 32 * j][4 * dc];
      #pragma unroll
      for (int i = 0; i < 4; ++i)
        #pragma unroll
        for (int j = 0; j < 4; ++j) {
          acc[i][j] = fmaf(qv[i].x, kv[j].x, acc[i][j]);
          acc[i][j] = fmaf(qv[i].y, kv[j].y, acc[i][j]);
          acc[i][j] = fmaf(qv[i].z, kv[j].z, acc[i][j]);
          acc[i][j] = fmaf(qv[i].w, kv[j].w, acc[i][j]);
        }
    }

    #pragma unroll
    for (int i = 0; i < 4; ++i) {
      const int row = 4 * tq + i;
      float* arow = attn_out + ((size_t)head * S_LEN + (q0 + row)) * S_LEN + kt * KT;
      #pragma unroll
      for (int j = 0; j < 4; ++j) {
        float e = (acc[i][j] < 0.0f) ? __expf(acc[i][j] * 0.125f) : 0.0f;
        es[row][tk + 32 * j] = e;
        arow[tk + 32 * j] = e * zi[i];         // coalesced 128B per (i,j)
      }
    }
    __syncthreads();                           // es visible to all before PV

    // PV: thread -> rows 4*tq+i, dims 2*tk..2*tk+1, loop k (unroll 4, b128 es reads)
    const float* Vt = Vh + (size_t)(kt * KT) * DK + 2 * tk;
    for (int k4 = 0; k4 < KT; k4 += 4) {
      float2 v0 = *(const float2*)(Vt + (size_t)(k4 + 0) * DK);
      float2 v1 = *(const float2*)(Vt + (size_t)(k4 + 1) * DK);
      float2 v2 = *(const float2*)(Vt + (size_t)(k4 + 2) * DK);
      float2 v3 = *(const float2*)(Vt + (size_t)(k4 + 3) * DK);
      #pragma unroll
      for (int i = 0; i < 4; ++i) {
        float4 ev = *(const float4*)&es[4 * tq + i][k4];   // broadcast within tq-group
        Cacc[i][0] = fmaf(ev.x, v0.x, Cacc[i][0]);
        Cacc[i][0] = fmaf(ev.y, v1.x, Cacc[i][0]);
        Cacc[i][0] = fmaf(ev.z, v2.x, Cacc[i][0]);
        Cacc[i][0] = fmaf(ev.w, v3.x, Cacc[i][0]);
        Cacc[i][1] = fmaf(ev.x, v0.y, Cacc[i][1]);
        Cacc[i][1] = fmaf(ev.y, v1.y, Cacc[i][1]);
        Cacc[i][1] = fmaf(ev.z, v2.y, Cacc[i][1]);
        Cacc[i][1] = fmaf(ev.w, v3.y, Cacc[i][1]);
      }
    }
  }

  // ---- context write: C = (sum e*V) / Z ----
  #pragma unroll
  for (int i = 0; i < 4; ++i) {
    float2 out;
    out.x = Cacc[i][0] * zi[i];
    out.y = Cacc[i][1] * zi[i];
    *(float2*)(ctx_out + ((size_t)head * S_LEN + (q0 + 4 * tq + i)) * DK + 2 * tk) = out;
  }
}

extern "C" void kernel_launch(void* const* d_in, const int* in_sizes, int n_in,
                              void* d_out, int out_size, void* d_ws, size_t ws_size,
                              hipStream_t stream) {
  const float* Q = (const float*)d_in[0];
  const float* K = (const float*)d_in[1];
  const float* V = (const float*)d_in[2];
  const int BH = in_sizes[0] / (S_LEN * DK);   // 24
  float* ctx  = (float*)d_out;                             // [BH,2048,64]
  float* attn = (float*)d_out + (size_t)BH * S_LEN * DK;   // [BH,2048,2048]
  dim3 grid(S_LEN / MT, BH);
  dim3 block(256);
  sdpa_kernel<<<grid, block, 0, stream>>>(Q, K, V, ctx, attn);
}

// Round 2
// 878.990 us; speedup vs baseline: 1.5240x; 1.5240x over previous
//
#include <hip/hip_runtime.h>
#include <hip/hip_bf16.h>
#include <math.h>

// B=2,H=12 -> 24 heads, S=2048, D=64, fp32 in; out = ctx[24,2048,64] ++ attn[24,2048,2048].
//
// Round 2: MFMA (bf16 3-plane split) for QK^T and PV.
//  - S^T = K*Q^T per WG (64 q-rows, sweep k in 64-slabs). C/D layout: col=lane&15 (q),
//    row=quad*4+reg (k) -> each thread owns 4 CONSECUTIVE k of one q -> float4 attn stores.
//  - Sign safety: |dot|<0.02 (worst-case 3-term split error <= 5.8e-3) -> recompute the
//    exact round-1 fmaf chain from global fp32 (bit-identical to the passing baseline).
//  - Pass A: Z row-sums (no recompute needed; flip -> 1/536 Z error -> ~3e-4 ctx, OK).
//  - PV: e->bf16 via es LDS tile (A-operand layout), Vt bf16 transposed+swizzled in ws.

#define S_LEN 2048
#define DK    64
#define MQ    64
#define KSLAB 64
#define NSTEP (S_LEN / KSLAB)   // 32
#define NQB   (S_LEN / MQ)      // 32
#define DOT_EPS 0.02f

typedef __attribute__((ext_vector_type(8))) short bf16x8;
typedef __attribute__((ext_vector_type(4))) float f32x4;

__device__ inline short f2bf(float x) {
  __hip_bfloat16 b = __float2bfloat16(x);
  return *reinterpret_cast<short*>(&b);
}
__device__ inline float bf2f(short s) {
  __hip_bfloat16 b = *reinterpret_cast<__hip_bfloat16*>(&s);
  return __bfloat162float(b);
}

// exact round-1 score chain: sequential fmaf over d=0..63 (bit-identical to baseline)
__device__ float exact_dot(const float* __restrict__ Qr, const float* __restrict__ Kr) {
  float acc = 0.f;
  #pragma unroll
  for (int d4 = 0; d4 < 16; ++d4) {
    float4 a = ((const float4*)Qr)[d4];
    float4 b = ((const float4*)Kr)[d4];
    acc = fmaf(a.x, b.x, acc);
    acc = fmaf(a.y, b.y, acc);
    acc = fmaf(a.z, b.z, acc);
    acc = fmaf(a.w, b.w, acc);
  }
  return acc;
}

// ---------------- prep kernel: build bf16 planes in ws ----------------
// QW: per head [q][plane2][64]                       (plain)
// KW: per head [kt16:128][row16][plane2][blk8^ (row&7)][8]
// VW: per head [slab:32][d64][blk8 ^ (d&7)][8]       (V transposed: Vt[d][k])
__global__ __launch_bounds__(256) void prep_kernel(
    const float* __restrict__ Q, const float* __restrict__ K, const float* __restrict__ V,
    short* __restrict__ qw, short* __restrict__ kw, short* __restrict__ vw, int secblocks) {
  const int bid = blockIdx.x, tid = threadIdx.x;
  if (bid < secblocks) {               // ---- Q section ----
    int flat = bid * 256 + tid;        // (head, q, b) over heads*2048*8
    int head = flat >> 14;
    int rem = flat & 16383;
    int q = rem >> 3, b = rem & 7;
    const float* src = Q + (size_t)(head * S_LEN + q) * DK + b * 8;
    bf16x8 hv, mv;
    #pragma unroll
    for (int i = 0; i < 8; ++i) {
      float x = src[i];
      short h = f2bf(x);
      short m = f2bf(x - bf2f(h));
      hv[i] = h; mv[i] = m;
    }
    short* dst = qw + (size_t)(head * S_LEN + q) * 128;
    *(bf16x8*)(dst + 0 * 64 + b * 8) = hv;
    *(bf16x8*)(dst + 1 * 64 + b * 8) = mv;
  } else if (bid < 2 * secblocks) {    // ---- K section ----
    int flat = (bid - secblocks) * 256 + tid;   // (head, kt, row, b)
    int head = flat >> 14;
    int rem = flat & 16383;
    int kt = rem >> 7;
    int row = (rem >> 3) & 15, b = rem & 7;
    const float* src = K + (size_t)(head * S_LEN + kt * 16 + row) * DK + b * 8;
    bf16x8 hv, mv;
    #pragma unroll
    for (int i = 0; i < 8; ++i) {
      float x = src[i];
      short h = f2bf(x);
      short m = f2bf(x - bf2f(h));
      hv[i] = h; mv[i] = m;
    }
    int bs = b ^ (row & 7);
    short* dst = kw + ((size_t)(head * 128 + kt) * 16 + row) * 128;
    *(bf16x8*)(dst + 0 * 64 + bs * 8) = hv;
    *(bf16x8*)(dst + 1 * 64 + bs * 8) = mv;
  } else {                             // ---- V section (transpose) ----
    int wid = (bid - 2 * secblocks) * 4 + (tid >> 6);  // (head, slab, b) over heads*32*8
    int lane = tid & 63;               // = d
    int head = wid >> 8;
    int rem = wid & 255;
    int slab = rem >> 3, b = rem & 7;
    bf16x8 vv;
    #pragma unroll
    for (int j = 0; j < 8; ++j)
      vv[j] = f2bf(V[(size_t)(head * S_LEN + slab * 64 + b * 8 + j) * DK + lane]);
    int bs = b ^ (lane & 7);
    *(bf16x8*)(vw + ((size_t)(head * 32 + slab) * 64 + lane) * 64 + bs * 8) = vv;
  }
}

// ---------------- main kernel ----------------
__global__ __launch_bounds__(256, 2) void sdpa_mfma(
    const float* __restrict__ Q, const float* __restrict__ K,
    const short* __restrict__ qw, const short* __restrict__ kw, const short* __restrict__ vw,
    float* __restrict__ ctx_out, float* __restrict__ attn_out) {
  __shared__ short Ks[8192];        // 4 k-tiles x [row16][plane2][blk8][8]
  __shared__ short Vt[2][4096];     // dbuf: [d64][blk8][8]
  __shared__ short es[4096];        // [q64][blk8 ^ (q&7)][8]  (e in bf16, A-layout)
  __shared__ float zred[4][MQ];
  __shared__ float zinv[MQ];

  const int head = blockIdx.y;
  const int q0 = blockIdx.x * MQ;
  const int tid = threadIdx.x;
  const int w = tid >> 6;
  const int lane = tid & 63;
  const int l15 = lane & 15;
  const int quad = lane >> 4;

  const short* QW = qw + (size_t)head * (S_LEN * 128);
  const short* KW = kw + (size_t)head * (128 * 16 * 128);
  const short* VW = vw + (size_t)head * (32 * 4096);
  const float* Qg = Q + (size_t)head * S_LEN * DK;
  const float* Kg = K + (size_t)head * S_LEN * DK;

  const f32x4 zf = {0.f, 0.f, 0.f, 0.f};

  // Q B-operand fragments, resident in registers for the whole sweep.
  // B[k=d][n=q]: lane: n=l15 -> q = qt*16+l15 ; k = c*32 + quad*8 + j
  bf16x8 qf[2][2][4];   // [plane][chunk][qt]
  #pragma unroll
  for (int p = 0; p < 2; ++p)
    #pragma unroll
    for (int c = 0; c < 2; ++c)
      #pragma unroll
      for (int qt = 0; qt < 4; ++qt)
        qf[p][c][qt] = *(const bf16x8*)(QW + (size_t)(q0 + qt * 16 + l15) * 128 + p * 64 + (c * 4 + quad) * 8);

  // QK^T (3-term split) for this thread's wave-tile: S^T tile w (k-rows 16w..16w+15)
  #define QK_COMPUTE(acc)                                                                      \
    {                                                                                          \
      bf16x8 ak[2][2];                                                                         \
      _Pragma("unroll")                                                                        \
      for (int p = 0; p < 2; ++p)                                                              \
        _Pragma("unroll")                                                                      \
        for (int c = 0; c < 2; ++c)                                                            \
          ak[p][c] = *(const bf16x8*)&Ks[w * 2048 + l15 * 128 + p * 64 +                       \
                                         (((c * 4 + quad) ^ (l15 & 7)) * 8)];                  \
      _Pragma("unroll")                                                                        \
      for (int qt = 0; qt < 4; ++qt)                                                           \
        _Pragma("unroll")                                                                      \
        for (int c = 0; c < 2; ++c) {                                                          \
          acc[qt] = __builtin_amdgcn_mfma_f32_16x16x32_bf16(ak[0][c], qf[0][c][qt], acc[qt], 0, 0, 0); \
          acc[qt] = __builtin_amdgcn_mfma_f32_16x16x32_bf16(ak[1][c], qf[0][c][qt], acc[qt], 0, 0, 0); \
          acc[qt] = __builtin_amdgcn_mfma_f32_16x16x32_bf16(ak[0][c], qf[1][c][qt], acc[qt], 0, 0, 0); \
        }                                                                                      \
    }

  // ================= pass A: Z =================
  float zp[4] = {0.f, 0.f, 0.f, 0.f};
  {
    const short* s = KW;   // step 0
    #pragma unroll
    for (int r = 0; r < 4; ++r)
      *(bf16x8*)&Ks[(tid + 256 * r) * 8] = *(const bf16x8*)(s + (tid + 256 * r) * 8);
  }
  __syncthreads();
  for (int step = 0; step < NSTEP; ++step) {
    bf16x8 sk[4];
    const bool more = (step + 1 < NSTEP);
    if (more) {
      const short* s = KW + (size_t)(step + 1) * 8192;
      #pragma unroll
      for (int r = 0; r < 4; ++r) sk[r] = *(const bf16x8*)(s + (tid + 256 * r) * 8);
    }
    f32x4 acc[4] = {zf, zf, zf, zf};
    QK_COMPUTE(acc);
    #pragma unroll
    for (int qt = 0; qt < 4; ++qt)
      #pragma unroll
      for (int r = 0; r < 4; ++r) {
        float d = acc[qt][r];
        zp[qt] += (d < 0.f) ? __expf(d * 0.125f) : 0.f;
      }
    __syncthreads();
    if (more) {
      #pragma unroll
      for (int r = 0; r < 4; ++r) *(bf16x8*)&Ks[(tid + 256 * r) * 8] = sk[r];
    }
    __syncthreads();
  }

  // Z reduce: quads hold disjoint k -> shfl over lane bits 4,5; waves via LDS
  #pragma unroll
  for (int qt = 0; qt < 4; ++qt) {
    float v = zp[qt];
    v += __shfl_xor(v, 16);
    v += __shfl_xor(v, 32);
    if (lane < 16) zred[w][qt * 16 + lane] = v;
  }
  __syncthreads();
  if (tid < MQ) {
    float Z = zred[0][tid] + zred[1][tid] + zred[2][tid] + zred[3][tid];
    zinv[tid] = 1.f / (Z + 1e-8f);
  }
  __syncthreads();
  float ziq[4], zctx[4];
  #pragma unroll
  for (int qt = 0; qt < 4; ++qt) ziq[qt] = zinv[qt * 16 + l15];
  #pragma unroll
  for (int r = 0; r < 4; ++r) zctx[r] = zinv[16 * w + quad * 4 + r];

  // ================= pass B: attn + PV =================
  f32x4 ctxa[4] = {zf, zf, zf, zf};   // [dt]; C rows q=16w+quad*4+reg, cols d=dt*16+l15
  {
    #pragma unroll
    for (int r = 0; r < 4; ++r)
      *(bf16x8*)&Ks[(tid + 256 * r) * 8] = *(const bf16x8*)(KW + (tid + 256 * r) * 8);
    #pragma unroll
    for (int r = 0; r < 2; ++r)
      *(bf16x8*)&Vt[0][(tid + 256 * r) * 8] = *(const bf16x8*)(VW + (tid + 256 * r) * 8);
  }
  __syncthreads();
  for (int step = 0; step < NSTEP; ++step) {
    const int cur = step & 1;
    f32x4 acc[4] = {zf, zf, zf, zf};
    QK_COMPUTE(acc);

    const int kbase = step * 64 + 16 * w + quad * 4;
    #pragma unroll
    for (int qt = 0; qt < 4; ++qt) {
      float e4[4];
      #pragma unroll
      for (int r = 0; r < 4; ++r) {
        float d = acc[qt][r];
        if (fabsf(d) < DOT_EPS) {   // rare (~0.2%): exact sign via round-1 chain
          d = exact_dot(Qg + (size_t)(q0 + qt * 16 + l15) * DK,
                        Kg + (size_t)(kbase + r) * DK);
        }
        e4[r] = (d < 0.f) ? __expf(d * 0.125f) : 0.f;
      }
      float4 av = {e4[0] * ziq[qt], e4[1] * ziq[qt], e4[2] * ziq[qt], e4[3] * ziq[qt]};
      *(float4*)(attn_out + (size_t)(head * S_LEN + q0 + qt * 16 + l15) * S_LEN + kbase) = av;
      // es write: row q=qt*16+l15, k-offset 16w+quad*4 (+r), 16B-block swizzle ^ (q&7)
      int qe = qt * 16 + l15;
      int blk = 2 * w + (quad >> 1);
      short* ep = &es[qe * 64 + ((blk ^ (qe & 7)) * 8) + (quad & 1) * 4];
      *(short4*)ep = make_short4(f2bf(e4[0]), f2bf(e4[1]), f2bf(e4[2]), f2bf(e4[3]));
    }
    __syncthreads();   // es complete; Ks consumed by QK

    bf16x8 sk[4], sv[2];
    const bool more = (step + 1 < NSTEP);
    if (more) {
      const short* s = KW + (size_t)(step + 1) * 8192;
      #pragma unroll
      for (int r = 0; r < 4; ++r) sk[r] = *(const bf16x8*)(s + (tid + 256 * r) * 8);
      const short* v = VW + (size_t)(step + 1) * 4096;
      #pragma unroll
      for (int r = 0; r < 2; ++r) sv[r] = *(const bf16x8*)(v + (tid + 256 * r) * 8);
    }

    // PV: wave w owns q-tile w. A = es (A[m=q][k]), B = Vt (B[k][n=d])
    {
      bf16x8 ea[2];
      const int qe = 16 * w + l15;
      #pragma unroll
      for (int c = 0; c < 2; ++c)
        ea[c] = *(const bf16x8*)&es[qe * 64 + (((c * 4 + quad) ^ (l15 & 7)) * 8)];
      #pragma unroll
      for (int dt = 0; dt < 4; ++dt) {
        const int de = dt * 16 + l15;
        #pragma unroll
        for (int c = 0; c < 2; ++c) {
          bf16x8 vb = *(const bf16x8*)&Vt[cur][de * 64 + (((c * 4 + quad) ^ (l15 & 7)) * 8)];
          ctxa[dt] = __builtin_amdgcn_mfma_f32_16x16x32_bf16(ea[c], vb, ctxa[dt], 0, 0, 0);
        }
      }
    }
    if (more) {
      #pragma unroll
      for (int r = 0; r < 4; ++r) *(bf16x8*)&Ks[(tid + 256 * r) * 8] = sk[r];
      #pragma unroll
      for (int r = 0; r < 2; ++r) *(bf16x8*)&Vt[cur ^ 1][(tid + 256 * r) * 8] = sv[r];
    }
    __syncthreads();   // staging + PV complete
  }

  // ctx store
  #pragma unroll
  for (int dt = 0; dt < 4; ++dt)
    #pragma unroll
    for (int r = 0; r < 4; ++r) {
      int q = 16 * w + quad * 4 + r;
      ctx_out[(size_t)(head * S_LEN + q0 + q) * DK + dt * 16 + l15] = ctxa[dt][r] * zctx[r];
    }
}

extern "C" void kernel_launch(void* const* d_in, const int* in_sizes, int n_in,
                              void* d_out, int out_size, void* d_ws, size_t ws_size,
                              hipStream_t stream) {
  const float* Q = (const float*)d_in[0];
  const float* K = (const float*)d_in[1];
  const float* V = (const float*)d_in[2];
  const int heads = in_sizes[0] / (S_LEN * DK);   // 24

  float* ctx = (float*)d_out;
  float* attn = (float*)d_out + (size_t)heads * S_LEN * DK;

  short* qw = (short*)d_ws;                                  // heads*2048*128 bf16
  short* kw = qw + (size_t)heads * S_LEN * 128;              // heads*128*16*128
  short* vw = kw + (size_t)heads * 128 * 16 * 128;           // heads*32*4096

  const int secblocks = heads * 64;                          // blocks per prep section
  prep_kernel<<<dim3(3 * secblocks), dim3(256), 0, stream>>>(Q, K, V, qw, kw, vw, secblocks);
  sdpa_mfma<<<dim3(NQB, heads), dim3(256), 0, stream>>>(Q, K, qw, kw, vw, ctx, attn);
}